// Round 8
// baseline (300.890 us; speedup 1.0000x reference)
//
#include <hip/hip_runtime.h>
#include <hip/hip_bf16.h>

typedef __bf16 bf16;
typedef __bf16 bf16x8 __attribute__((ext_vector_type(8)));
typedef __bf16 bf16x4 __attribute__((ext_vector_type(4)));
typedef float  f32x4  __attribute__((ext_vector_type(4)));

#define LDS_ASYNC16(g, l)                                            \
  __builtin_amdgcn_global_load_lds(                                  \
      (const __attribute__((address_space(1))) void*)(g),            \
      (__attribute__((address_space(3))) void*)(l), 16, 0, 0)

// compiler memory fence: pins issue order of surrounding memory ops
#define MFENCE asm volatile("" ::: "memory")

// log2(e) / 32  — folded into Q at GEMM1 epilogue so flash uses exp2 directly
#define QSCALE 0.04508421995f

// ---------------------------------------------------------------- convert (x, w_qkv, w_proj in one launch)
__global__ void cvt3_f32_bf16(const float* __restrict__ i0, bf16* __restrict__ o0, int n0,
                              const float* __restrict__ i1, bf16* __restrict__ o1, int n1,
                              const float* __restrict__ i2, bf16* __restrict__ o2, int n2) {
  int i = blockIdx.x * blockDim.x + threadIdx.x;
  const float* in;
  bf16* out;
  if (i < n0) {
    in = i0; out = o0;
  } else if (i < n0 + n1) {
    i -= n0; in = i1; out = o1;
  } else {
    i -= n0 + n1;
    if (i >= n2) return;
    in = i2; out = o2;
  }
  float4 v = ((const float4*)in)[i];
  bf16x4 o = {(bf16)v.x, (bf16)v.y, (bf16)v.z, (bf16)v.w};
  ((bf16x4*)out)[i] = o;
}

// ---------------------------------------------------------------- GEMM (B^T input)
// R8: A via LDS (R4's verified global_load_lds path), B DIRECT FROM GLOBAL
// into registers (L2-hot weights). R7's NaN was a prologue race: no fence
// between the A-DMAs and the B reg-loads -> compiler could issue B first ->
// vmcnt(4) left A-DMAs outstanding -> stale LDS. R8 hardens the protocol:
//   * prologue: fence between DMA group and LB group, then vmcnt(0)
//     (order-independent full drain, one-time cost);
//   * fence immediately after every s_barrier (raw s_barrier is NOT a
//     compiler memory fence; pins ST_A below the read-done barrier and
//     ds_reads below the tile-ready barrier);
//   * _Pragma unroll on macro loops (static reg indexing, rule #20).
// Steady state (re-derived from empty prologue queue): BODY(kt) issues
// ST_A(kt+2):2 then LB(kt+2):4; end-of-body vmcnt(6) drains exactly tile
// kt+1's 6 chunks. Tail: vmcnt(0) at kt==KT-2.
// MODE 0: write fp32 to outf (row-major M x N)
// MODE 1: qkv split epilogue -> q*QSCALE[B,H,T,hd], k[B,H,T,hd], v^T[B,H,hd,T]
template <int MODE>
__global__ __launch_bounds__(256, 3) void gemm_bt(
    const bf16* __restrict__ A, const bf16* __restrict__ B,
    const float* __restrict__ bias, float* __restrict__ outf,
    bf16* __restrict__ oq, bf16* __restrict__ ok, bf16* __restrict__ ov,
    int M, int N, int K) {
  __shared__ __align__(16) bf16 As[2][128 * 32];  // 8KB per buf, 16KB total
  const int tid = threadIdx.x;
  const int wave = tid >> 6, lane = tid & 63;
  const int quad = lane >> 4, l15 = lane & 15;
  const int bm = blockIdx.x * 128, bn = blockIdx.y * 128;
  const int wrow = (wave >> 1) << 6, wcol = (wave & 1) << 6;

  f32x4 acc[4][4] = {};

  // A staging (R4-verified): pre-swizzled global granule, linear LDS dest;
  // read-side XOR cancels (conflicts == 0 measured).
  const int csw = ((tid & 3) ^ ((tid >> 3) & 3)) * 8;
  const bf16* gA = A + (size_t)(bm + (tid >> 2)) * K + csw;
  char* lA = (char*)As + wave * 1024;  // + lane*16 appended by HW
  const size_t K64 = (size_t)K * 64;
  const int KT = K >> 5;  // BK=32 tiles; K=1024 -> 32 (even, >=4)

#define ST_A(kt, cb) do {                                 \
    const bf16* a_ = gA + (size_t)(kt) * 32;              \
    LDS_ASYNC16(a_, lA + (cb) * 8192);                    \
    LDS_ASYNC16(a_ + K64, lA + (cb) * 8192 + 4096);       \
  } while (0)

  // B fragment pointers: row (bn+wcol+ni*16+l15), k-chunk quad*8 (16B aligned)
  const bf16* gB0 = B + (size_t)(bn + wcol + 0 + l15) * K + quad * 8;
  const bf16* gB1 = B + (size_t)(bn + wcol + 16 + l15) * K + quad * 8;
  const bf16* gB2 = B + (size_t)(bn + wcol + 32 + l15) * K + quad * 8;
  const bf16* gB3 = B + (size_t)(bn + wcol + 48 + l15) * K + quad * 8;

#define LB(dst, kt) do {                                              \
    dst[0] = *(const bf16x8*)(gB0 + (size_t)(kt) * 32);               \
    dst[1] = *(const bf16x8*)(gB1 + (size_t)(kt) * 32);               \
    dst[2] = *(const bf16x8*)(gB2 + (size_t)(kt) * 32);               \
    dst[3] = *(const bf16x8*)(gB3 + (size_t)(kt) * 32);               \
  } while (0)

  bf16x8 be[4], bo[4];  // named double-buffer for B (static indexing)

  // prologue: DMA group, FENCE, reg-load group, full drain (order-proof)
  ST_A(0, 0);
  ST_A(1, 1);
  MFENCE;
  LB(be, 0);
  LB(bo, 1);
  asm volatile("s_waitcnt vmcnt(0)" ::: "memory");
  __builtin_amdgcn_s_barrier();
  MFENCE;

  const int gsw = (quad ^ ((l15 >> 1) & 3)) * 16;  // A read swizzle (64B rows)

  // body for one K-step; breg = this step's B regs (be even kt, bo odd)
#define BODY(kt, breg) do {                                               \
    const char* bA_ = (const char*)As + ((kt) & 1) * 8192;                \
    bf16x8 af[4];                                                         \
    _Pragma("unroll")                                                     \
    for (int mi = 0; mi < 4; ++mi)                                        \
      af[mi] = *(const bf16x8*)(bA_ + (wrow + mi * 16 + l15) * 64 + gsw); \
    asm volatile("s_waitcnt lgkmcnt(0)" ::: "memory");                    \
    __builtin_amdgcn_s_barrier();          /* buf (kt&1) free */          \
    MFENCE;                                /* ST_A stays below barrier */ \
    if ((kt) + 2 < KT) ST_A((kt) + 2, (kt) & 1);                          \
    MFENCE;                                /* pin ST_A before LB */       \
    __builtin_amdgcn_s_setprio(1);                                        \
    _Pragma("unroll")                                                     \
    for (int mi = 0; mi < 4; ++mi)                                        \
      _Pragma("unroll")                                                   \
      for (int ni = 0; ni < 4; ++ni)                                      \
        acc[mi][ni] = __builtin_amdgcn_mfma_f32_16x16x32_bf16(            \
            af[mi], breg[ni], acc[mi][ni], 0, 0, 0);                      \
    __builtin_amdgcn_s_setprio(0);                                        \
    if ((kt) + 2 < KT) LB(breg, (kt) + 2); /* reuse freed regs */         \
    MFENCE;                                                               \
    if ((kt) + 1 < KT) {                                                  \
      if ((kt) + 2 < KT)                                                  \
        asm volatile("s_waitcnt vmcnt(6)" ::: "memory");                  \
      else                                                                \
        asm volatile("s_waitcnt vmcnt(0)" ::: "memory");                  \
      __builtin_amdgcn_s_barrier();        /* tile kt+1 ready for all */  \
      MFENCE;                              /* next ds_reads stay below */ \
    }                                                                     \
  } while (0)

#pragma unroll 1
  for (int kt = 0; kt < KT; kt += 2) {
    BODY(kt, be);
    BODY(kt + 1, bo);
  }
#undef BODY
#undef LB
#undef ST_A

#pragma unroll
  for (int mi = 0; mi < 4; ++mi) {
    const int row0 = bm + wrow + mi * 16 + quad * 4;  // C row = quad*4+reg
#pragma unroll
    for (int ni = 0; ni < 4; ++ni) {
      const int col = bn + wcol + ni * 16 + l15;      // C col = lane&15
      const float bv = bias[col];
      if (MODE == 0) {
#pragma unroll
        for (int r = 0; r < 4; ++r)
          outf[(size_t)(row0 + r) * N + col] = acc[mi][ni][r] + bv;
      } else {
        const int part = col >> 10;
        const int cn = col & 1023, h = cn >> 6, d = cn & 63;
        const int b = row0 >> 11, t0 = row0 & 2047;
        if (part == 2) {
          bf16x4 pk = {(bf16)(acc[mi][ni][0] + bv), (bf16)(acc[mi][ni][1] + bv),
                       (bf16)(acc[mi][ni][2] + bv), (bf16)(acc[mi][ni][3] + bv)};
          *(bf16x4*)(ov + ((size_t)(b * 16 + h) * 64 + d) * 2048 + t0) = pk;
        } else {
          const float sc = part ? 1.0f : QSCALE;
          bf16* dst = (part ? ok : oq) + ((size_t)(b * 16 + h) * 2048 + t0) * 64 + d;
#pragma unroll
          for (int r = 0; r < 4; ++r)
            dst[(size_t)r * 64] = (bf16)((acc[mi][ni][r] + bv) * sc);
        }
      }
    }
  }
}

// ---------------------------------------------------------------- flash attention
// R1/R4-verified version (best measured): 256 thr, grid (B*H, 16),
// heavy-first; PV via 16x16x32 with pre-permuted V^T in LDS.
__global__ __launch_bounds__(256) void flash_attn(
    const bf16* __restrict__ qb, const bf16* __restrict__ kb,
    const bf16* __restrict__ vt, bf16* __restrict__ ob) {
  constexpr int T = 2048;
  __shared__ bf16 Ks[2][64 * 72];
  __shared__ bf16 Vs[2][64 * 72];      // transposed + k-permuted: [d][p(key)]
  __shared__ float Ls[4][2][4][16];    // per-wave l partials
  const int tid = threadIdx.x, wave = tid >> 6, lane = tid & 63;
  const int quad = lane >> 4, l15 = lane & 15;
  const int bh = blockIdx.x;
  const int b = bh >> 4, h = bh & 15;
  const bf16* qbase = qb + (size_t)bh * T * 64;
  const bf16* kbase = kb + (size_t)bh * T * 64;
  const bf16* vbase = vt + (size_t)bh * 64 * T;
  const int srow = tid >> 3, sc = (tid & 7) * 8;  // srow 0..31

  // permuted base position for this thread's 8-key V chunk (sc multiple of 8)
  const int vp0 = (sc & ~31) | ((sc & 8) << 1) | ((sc & 16) >> 2);

  const int qt = 15 - (int)blockIdx.y;  // heavy tiles first
  const int q0 = qt * 128 + wave * 32;

  bf16x8 qf[2][2];  // B-operand: Q[q=l15][k=quad*8+j]
#pragma unroll
  for (int qi = 0; qi < 2; ++qi)
#pragma unroll
    for (int ks = 0; ks < 2; ++ks)
      qf[qi][ks] = *(const bf16x8*)(qbase + (size_t)(q0 + qi * 16 + l15) * 64 +
                                    ks * 32 + quad * 8);

  f32x4 lsumv[2] = {};
  f32x4 oacc[2][4] = {};  // [qi][di], C-layout row=q-local, col=d-local

  const int nkt = 2 * qt + 2;
  const int ktp = q0 >> 6;  // this wave's diagonal tile

  // prologue: stage tile 0 into buffer 0
  {
    uint4 k0 = *(const uint4*)(kbase + (size_t)srow * 64 + sc);
    uint4 k1 = *(const uint4*)(kbase + (size_t)(srow + 32) * 64 + sc);
    uint4 v0 = *(const uint4*)(vbase + (size_t)srow * T + sc);
    uint4 v1 = *(const uint4*)(vbase + (size_t)(srow + 32) * T + sc);
    *(uint4*)&Ks[0][srow * 72 + sc] = k0;
    *(uint4*)&Ks[0][(srow + 32) * 72 + sc] = k1;
    *(uint2*)&Vs[0][srow * 72 + vp0] = make_uint2(v0.x, v0.y);
    *(uint2*)&Vs[0][srow * 72 + vp0 + 8] = make_uint2(v0.z, v0.w);
    *(uint2*)&Vs[0][(srow + 32) * 72 + vp0] = make_uint2(v1.x, v1.y);
    *(uint2*)&Vs[0][(srow + 32) * 72 + vp0 + 8] = make_uint2(v1.z, v1.w);
  }

#pragma unroll 1
  for (int kt = 0; kt < nkt; ++kt) {
    __syncthreads();  // cur buffer writes visible; prev reads done
    const int cur = kt & 1;
    const bool pre = (kt + 1) < nkt;
    uint4 pk0, pk1, pv0, pv1;
    if (pre) {  // prefetch next tile into registers (overlaps compute)
      const bf16* kp = kbase + (size_t)(kt + 1) * 64 * 64;
      const bf16* vp = vbase + (kt + 1) * 64;
      pk0 = *(const uint4*)(kp + (size_t)srow * 64 + sc);
      pk1 = *(const uint4*)(kp + (size_t)(srow + 32) * 64 + sc);
      pv0 = *(const uint4*)(vp + (size_t)srow * T + sc);
      pv1 = *(const uint4*)(vp + (size_t)(srow + 32) * T + sc);
    }
    if (kt <= ktp) {
      // S^T = K·Q^T : st[ki][qi], row=k-local(quad*4+r), col=q(l15)
      f32x4 st[4][2];
      __builtin_amdgcn_s_setprio(1);
#pragma unroll
      for (int ki = 0; ki < 4; ++ki) {
        bf16x8 kfa = *(const bf16x8*)&Ks[cur][(ki * 16 + l15) * 72 + quad * 8];
        bf16x8 kfb =
            *(const bf16x8*)&Ks[cur][(ki * 16 + l15) * 72 + 32 + quad * 8];
#pragma unroll
        for (int qi = 0; qi < 2; ++qi) {
          f32x4 a = {0.f, 0.f, 0.f, 0.f};
          a = __builtin_amdgcn_mfma_f32_16x16x32_bf16(kfa, qf[qi][0], a, 0, 0, 0);
          a = __builtin_amdgcn_mfma_f32_16x16x32_bf16(kfb, qf[qi][1], a, 0, 0, 0);
          st[ki][qi] = a;
        }
      }
      __builtin_amdgcn_s_setprio(0);
      if (kt == ktp) {  // mask only the diagonal tile
#pragma unroll
        for (int ki = 0; ki < 4; ++ki)
#pragma unroll
          for (int qi = 0; qi < 2; ++qi)
#pragma unroll
            for (int r = 0; r < 4; ++r) {
              const int kcol = kt * 64 + ki * 16 + quad * 4 + r;
              const int qrow = q0 + qi * 16 + l15;
              if (kcol > qrow) st[ki][qi][r] = -__builtin_inff();
            }
      }
      // p = exp2(s); per-lane partial row sums (q=l15)
#pragma unroll
      for (int ki = 0; ki < 4; ++ki)
#pragma unroll
        for (int qi = 0; qi < 2; ++qi) {
#pragma unroll
          for (int r = 0; r < 4; ++r)
            st[ki][qi][r] = __builtin_amdgcn_exp2f(st[ki][qi][r]);
          lsumv[qi] += st[ki][qi];
        }
      // pack P into bf16x8 A-fragments for 16x16x32 PV
      bf16x8 pa8[2][2];
#pragma unroll
      for (int ki2 = 0; ki2 < 2; ++ki2)
#pragma unroll
        for (int qi = 0; qi < 2; ++qi) {
          bf16x8 p;
#pragma unroll
          for (int r = 0; r < 4; ++r) {
            p[r] = (bf16)st[2 * ki2][qi][r];
            p[r + 4] = (bf16)st[2 * ki2 + 1][qi][r];
          }
          pa8[ki2][qi] = p;
        }
      // PV: O[q][d] += P·V via 16x16x32; V read as one b128 per (di,ki2)
      __builtin_amdgcn_s_setprio(1);
#pragma unroll
      for (int di = 0; di < 4; ++di)
#pragma unroll
        for (int ki2 = 0; ki2 < 2; ++ki2) {
          bf16x8 vv = *(const bf16x8*)&Vs[cur][(di * 16 + l15) * 72 + ki2 * 32 +
                                              quad * 8];
#pragma unroll
          for (int qi = 0; qi < 2; ++qi)
            oacc[qi][di] = __builtin_amdgcn_mfma_f32_16x16x32_bf16(
                pa8[ki2][qi], vv, oacc[qi][di], 0, 0, 0);
        }
      __builtin_amdgcn_s_setprio(0);
    }
    if (pre) {  // write prefetched tile into the other buffer
      const int nxt = cur ^ 1;
      *(uint4*)&Ks[nxt][srow * 72 + sc] = pk0;
      *(uint4*)&Ks[nxt][(srow + 32) * 72 + sc] = pk1;
      *(uint2*)&Vs[nxt][srow * 72 + vp0] = make_uint2(pv0.x, pv0.y);
      *(uint2*)&Vs[nxt][srow * 72 + vp0 + 8] = make_uint2(pv0.z, pv0.w);
      *(uint2*)&Vs[nxt][(srow + 32) * 72 + vp0] = make_uint2(pv1.x, pv1.y);
      *(uint2*)&Vs[nxt][(srow + 32) * 72 + vp0 + 8] = make_uint2(pv1.z, pv1.w);
    }
  }

  // epilogue: transpose l partials (q=l15 -> q=quad*4+r), divide, store
#pragma unroll
  for (int qi = 0; qi < 2; ++qi)
    Ls[wave][qi][quad][l15] =
        lsumv[qi][0] + lsumv[qi][1] + lsumv[qi][2] + lsumv[qi][3];
  // wave-private region; compiler inserts lgkmcnt before dependent reads
#pragma unroll
  for (int qi = 0; qi < 2; ++qi)
#pragma unroll
    for (int r = 0; r < 4; ++r) {
      const int rloc = quad * 4 + r;
      const float l = Ls[wave][qi][0][rloc] + Ls[wave][qi][1][rloc] +
                      Ls[wave][qi][2][rloc] + Ls[wave][qi][3][rloc];
      const float inv = 1.f / l;
      const int t = q0 + qi * 16 + rloc;
#pragma unroll
      for (int di = 0; di < 4; ++di) {
        const int d = di * 16 + l15;
        ob[((size_t)b * 2048 + t) * 1024 + h * 64 + d] =
            (bf16)(oacc[qi][di][r] * inv);
      }
    }
}

// ---------------------------------------------------------------- launch
extern "C" void kernel_launch(void* const* d_in, const int* in_sizes, int n_in,
                              void* d_out, int out_size, void* d_ws,
                              size_t ws_size, hipStream_t stream) {
  const float* x = (const float*)d_in[0];
  const float* w_qkv = (const float*)d_in[1];
  const float* b_qkv = (const float*)d_in[2];
  const float* w_proj = (const float*)d_in[3];
  const float* b_proj = (const float*)d_in[4];
  float* out = (float*)d_out;

  const int B = 4, T = 2048, C = 1024;
  const size_t nx = (size_t)B * T * C;  // 8388608

  char* ws = (char*)d_ws;
  bf16* xb = (bf16*)ws;      ws += nx * 2;
  bf16* wqkvb = (bf16*)ws;   ws += (size_t)3 * C * C * 2;
  bf16* wprojb = (bf16*)ws;  ws += (size_t)C * C * 2;
  bf16* qb = (bf16*)ws;      ws += nx * 2;
  bf16* kbuf = (bf16*)ws;    ws += nx * 2;
  bf16* vtb = (bf16*)ws;     ws += nx * 2;
  bf16* attb = (bf16*)ws;    ws += nx * 2;   // total 88 MB

  const int n0 = (int)(nx / 4), n1 = 3 * C * C / 4, n2 = C * C / 4;
  cvt3_f32_bf16<<<(n0 + n1 + n2 + 255) / 256, 256, 0, stream>>>(
      x, xb, n0, w_qkv, wqkvb, n1, w_proj, wprojb, n2);

  dim3 g1(64, 24);  // M/128, 3C/128 — 1536 blocks
  gemm_bt<1><<<g1, 256, 0, stream>>>(xb, wqkvb, b_qkv, nullptr, qb, kbuf, vtb,
                                     B * T, 3 * C, C);
  dim3 g2(64, 16);  // B*H, one q-tile per block, heavy first
  flash_attn<<<g2, 256, 0, stream>>>(qb, kbuf, vtb, attb);

  dim3 g3(64, 8);   // M/128, C/128 — 512 blocks
  gemm_bt<0><<<g3, 256, 0, stream>>>(attb, wprojb, b_proj, out, nullptr,
                                     nullptr, nullptr, B * T, C, C);
}

// Round 9
// 245.277 us; speedup vs baseline: 1.2267x; 1.2267x over previous
//
#include <hip/hip_runtime.h>
#include <hip/hip_bf16.h>

typedef __bf16 bf16;
typedef __bf16 bf16x8 __attribute__((ext_vector_type(8)));
typedef __bf16 bf16x4 __attribute__((ext_vector_type(4)));
typedef float  f32x4  __attribute__((ext_vector_type(4)));

#define LDS_ASYNC16(g, l)                                            \
  __builtin_amdgcn_global_load_lds(                                  \
      (const __attribute__((address_space(1))) void*)(g),            \
      (__attribute__((address_space(3))) void*)(l), 16, 0, 0)

// log2(e) / 32  — folded into Q at GEMM1 epilogue so flash uses exp2 directly
#define QSCALE 0.04508421995f

// ---------------------------------------------------------------- convert (x, w_qkv, w_proj in one launch)
__global__ void cvt3_f32_bf16(const float* __restrict__ i0, bf16* __restrict__ o0, int n0,
                              const float* __restrict__ i1, bf16* __restrict__ o1, int n1,
                              const float* __restrict__ i2, bf16* __restrict__ o2, int n2) {
  int i = blockIdx.x * blockDim.x + threadIdx.x;
  const float* in;
  bf16* out;
  if (i < n0) {
    in = i0; out = o0;
  } else if (i < n0 + n1) {
    i -= n0; in = i1; out = o1;
  } else {
    i -= n0 + n1;
    if (i >= n2) return;
    in = i2; out = o2;
  }
  float4 v = ((const float4*)in)[i];
  bf16x4 o = {(bf16)v.x, (bf16)v.y, (bf16)v.z, (bf16)v.w};
  ((bf16x4*)out)[i] = o;
}

// ---------------------------------------------------------------- GEMM (B^T input)
// R4 kernel VERBATIM (best measured: gemm1 74.5us, conflicts=0, VGPR 64).
// Verdict after R2-R8 structure sweep (8-phase, 256², counted-vmcnt deep
// pipe, B-in-regs): all neutral or worse on this K=1024 shape. The ~700 TF
// level is this shape's practical ceiling for LDS-staged 2-phase schedules;
// do not restructure further.
template <int MODE>
__global__ __launch_bounds__(256, 4) void gemm_bt(
    const bf16* __restrict__ A, const bf16* __restrict__ B,
    const float* __restrict__ bias, float* __restrict__ outf,
    bf16* __restrict__ oq, bf16* __restrict__ ok, bf16* __restrict__ ov,
    int M, int N, int K) {
  __shared__ __align__(16) bf16 As[2][128 * 32];  // 8KB per buf
  __shared__ __align__(16) bf16 Bs[2][128 * 32];  // total 32KB
  const int tid = threadIdx.x;
  const int wave = tid >> 6, lane = tid & 63;
  const int quad = lane >> 4, l15 = lane & 15;
  const int bm = blockIdx.x * 128, bn = blockIdx.y * 128;
  const int wrow = (wave >> 1) << 6, wcol = (wave & 1) << 6;

  f32x4 acc[4][4] = {};

  const int csw = ((tid & 3) ^ ((tid >> 3) & 3)) * 8;
  const bf16* gA = A + (size_t)(bm + (tid >> 2)) * K + csw;
  const bf16* gB = B + (size_t)(bn + (tid >> 2)) * K + csw;
  char* lA = (char*)As + wave * 1024;  // + lane*16 appended by HW
  char* lB = (char*)Bs + wave * 1024;
  const size_t K64 = (size_t)K * 64;
  const int KT = K >> 5;  // BK=32 tiles

#define ST(kt, cb) do {                                   \
    const bf16* a_ = gA + (size_t)(kt) * 32;              \
    const bf16* b_ = gB + (size_t)(kt) * 32;              \
    LDS_ASYNC16(a_, lA + (cb) * 8192);                    \
    LDS_ASYNC16(a_ + K64, lA + (cb) * 8192 + 4096);       \
    LDS_ASYNC16(b_, lB + (cb) * 8192);                    \
    LDS_ASYNC16(b_ + K64, lB + (cb) * 8192 + 4096);       \
  } while (0)

  ST(0, 0);
  ST(1, 1);
  asm volatile("s_waitcnt vmcnt(4)" ::: "memory");
  __builtin_amdgcn_s_barrier();

  const int gsw = (quad ^ ((l15 >> 1) & 3)) * 16;  // byte offset in 64B row

#pragma unroll 1
  for (int kt = 0; kt < KT; ++kt) {
    const int c = kt & 1;
    const char* bA = (const char*)As + c * 8192;
    const char* bB = (const char*)Bs + c * 8192;
    bf16x8 af[4], bfr[4];
#pragma unroll
    for (int mi = 0; mi < 4; ++mi)
      af[mi] = *(const bf16x8*)(bA + (wrow + mi * 16 + l15) * 64 + gsw);
#pragma unroll
    for (int ni = 0; ni < 4; ++ni)
      bfr[ni] = *(const bf16x8*)(bB + (wcol + ni * 16 + l15) * 64 + gsw);
    asm volatile("s_waitcnt lgkmcnt(0)" ::: "memory");
    __builtin_amdgcn_s_barrier();           // all waves done reading buf c
    if (kt + 2 < KT) ST(kt + 2, c);         // refill freed buffer
    __builtin_amdgcn_s_setprio(1);
#pragma unroll
    for (int mi = 0; mi < 4; ++mi)
#pragma unroll
      for (int ni = 0; ni < 4; ++ni)
        acc[mi][ni] = __builtin_amdgcn_mfma_f32_16x16x32_bf16(
            af[mi], bfr[ni], acc[mi][ni], 0, 0, 0);
    __builtin_amdgcn_s_setprio(0);
    if (kt + 1 < KT) {                      // tile kt+1 resident for all
      if (kt + 2 < KT)
        asm volatile("s_waitcnt vmcnt(4)" ::: "memory");
      else
        asm volatile("s_waitcnt vmcnt(0)" ::: "memory");
      __builtin_amdgcn_s_barrier();
    }
  }
#undef ST

#pragma unroll
  for (int mi = 0; mi < 4; ++mi) {
    const int row0 = bm + wrow + mi * 16 + quad * 4;  // C row = quad*4+reg
#pragma unroll
    for (int ni = 0; ni < 4; ++ni) {
      const int col = bn + wcol + ni * 16 + l15;      // C col = lane&15
      const float bv = bias[col];
      if (MODE == 0) {
#pragma unroll
        for (int r = 0; r < 4; ++r)
          outf[(size_t)(row0 + r) * N + col] = acc[mi][ni][r] + bv;
      } else {
        const int part = col >> 10;
        const int cn = col & 1023, h = cn >> 6, d = cn & 63;
        const int b = row0 >> 11, t0 = row0 & 2047;
        if (part == 2) {
          bf16x4 pk = {(bf16)(acc[mi][ni][0] + bv), (bf16)(acc[mi][ni][1] + bv),
                       (bf16)(acc[mi][ni][2] + bv), (bf16)(acc[mi][ni][3] + bv)};
          *(bf16x4*)(ov + ((size_t)(b * 16 + h) * 64 + d) * 2048 + t0) = pk;
        } else {
          const float sc = part ? 1.0f : QSCALE;
          bf16* dst = (part ? ok : oq) + ((size_t)(b * 16 + h) * 2048 + t0) * 64 + d;
#pragma unroll
          for (int r = 0; r < 4; ++r)
            dst[(size_t)r * 64] = (bf16)((acc[mi][ni][r] + bv) * sc);
        }
      }
    }
  }
}

// ---------------------------------------------------------------- flash attention
// R9: R1/R4-verified kernel with ONE change — the y->qt map is permuted so
// per-CU load balances. All 1024 blocks are co-resident (4/CU capacity
// exactly), so makespan = max over CUs of its 4 blocks' summed work. With
// round-robin dispatch (id = x + 64y), CU c gets y in {c>>6, +4, +8, +12}.
// Old monotone map: qt sums = 80 - 8*(c>>6)  (range 56..80, mean 68).
// New map [15,14,13,12, 0,1,2,3, 11,10,9,8, 4,5,6,7]: every {y,y+4,y+8,y+12}
// class sums qt = 30 -> every CU carries 68 units. Neutral if dispatch
// differs; ~18% makespan cut if model holds.
__global__ __launch_bounds__(256) void flash_attn(
    const bf16* __restrict__ qb, const bf16* __restrict__ kb,
    const bf16* __restrict__ vt, bf16* __restrict__ ob) {
  constexpr int T = 2048;
  __shared__ bf16 Ks[2][64 * 72];
  __shared__ bf16 Vs[2][64 * 72];      // transposed + k-permuted: [d][p(key)]
  __shared__ float Ls[4][2][4][16];    // per-wave l partials
  const int tid = threadIdx.x, wave = tid >> 6, lane = tid & 63;
  const int quad = lane >> 4, l15 = lane & 15;
  const int bh = blockIdx.x;
  const int b = bh >> 4, h = bh & 15;
  const bf16* qbase = qb + (size_t)bh * T * 64;
  const bf16* kbase = kb + (size_t)bh * T * 64;
  const bf16* vbase = vt + (size_t)bh * 64 * T;
  const int srow = tid >> 3, sc = (tid & 7) * 8;  // srow 0..31

  // permuted base position for this thread's 8-key V chunk (sc multiple of 8)
  const int vp0 = (sc & ~31) | ((sc & 8) << 1) | ((sc & 16) >> 2);

  // balanced y->qt map: {y, y+4, y+8, y+12} always sums to 30
  const int y = (int)blockIdx.y, g = y >> 2, r4 = y & 3;
  const int qt = (g == 0) ? 15 - r4 : (g == 1) ? r4 : (g == 2) ? 11 - r4 : 4 + r4;
  const int q0 = qt * 128 + wave * 32;

  bf16x8 qf[2][2];  // B-operand: Q[q=l15][k=quad*8+j]
#pragma unroll
  for (int qi = 0; qi < 2; ++qi)
#pragma unroll
    for (int ks = 0; ks < 2; ++ks)
      qf[qi][ks] = *(const bf16x8*)(qbase + (size_t)(q0 + qi * 16 + l15) * 64 +
                                    ks * 32 + quad * 8);

  f32x4 lsumv[2] = {};
  f32x4 oacc[2][4] = {};  // [qi][di], C-layout row=q-local, col=d-local

  const int nkt = 2 * qt + 2;
  const int ktp = q0 >> 6;  // this wave's diagonal tile

  // prologue: stage tile 0 into buffer 0
  {
    uint4 k0 = *(const uint4*)(kbase + (size_t)srow * 64 + sc);
    uint4 k1 = *(const uint4*)(kbase + (size_t)(srow + 32) * 64 + sc);
    uint4 v0 = *(const uint4*)(vbase + (size_t)srow * T + sc);
    uint4 v1 = *(const uint4*)(vbase + (size_t)(srow + 32) * T + sc);
    *(uint4*)&Ks[0][srow * 72 + sc] = k0;
    *(uint4*)&Ks[0][(srow + 32) * 72 + sc] = k1;
    *(uint2*)&Vs[0][srow * 72 + vp0] = make_uint2(v0.x, v0.y);
    *(uint2*)&Vs[0][srow * 72 + vp0 + 8] = make_uint2(v0.z, v0.w);
    *(uint2*)&Vs[0][(srow + 32) * 72 + vp0] = make_uint2(v1.x, v1.y);
    *(uint2*)&Vs[0][(srow + 32) * 72 + vp0 + 8] = make_uint2(v1.z, v1.w);
  }

#pragma unroll 1
  for (int kt = 0; kt < nkt; ++kt) {
    __syncthreads();  // cur buffer writes visible; prev reads done
    const int cur = kt & 1;
    const bool pre = (kt + 1) < nkt;
    uint4 pk0, pk1, pv0, pv1;
    if (pre) {  // prefetch next tile into registers (overlaps compute)
      const bf16* kp = kbase + (size_t)(kt + 1) * 64 * 64;
      const bf16* vp = vbase + (kt + 1) * 64;
      pk0 = *(const uint4*)(kp + (size_t)srow * 64 + sc);
      pk1 = *(const uint4*)(kp + (size_t)(srow + 32) * 64 + sc);
      pv0 = *(const uint4*)(vp + (size_t)srow * T + sc);
      pv1 = *(const uint4*)(vp + (size_t)(srow + 32) * T + sc);
    }
    if (kt <= ktp) {
      // S^T = K·Q^T : st[ki][qi], row=k-local(quad*4+r), col=q(l15)
      f32x4 st[4][2];
      __builtin_amdgcn_s_setprio(1);
#pragma unroll
      for (int ki = 0; ki < 4; ++ki) {
        bf16x8 kfa = *(const bf16x8*)&Ks[cur][(ki * 16 + l15) * 72 + quad * 8];
        bf16x8 kfb =
            *(const bf16x8*)&Ks[cur][(ki * 16 + l15) * 72 + 32 + quad * 8];
#pragma unroll
        for (int qi = 0; qi < 2; ++qi) {
          f32x4 a = {0.f, 0.f, 0.f, 0.f};
          a = __builtin_amdgcn_mfma_f32_16x16x32_bf16(kfa, qf[qi][0], a, 0, 0, 0);
          a = __builtin_amdgcn_mfma_f32_16x16x32_bf16(kfb, qf[qi][1], a, 0, 0, 0);
          st[ki][qi] = a;
        }
      }
      __builtin_amdgcn_s_setprio(0);
      if (kt == ktp) {  // mask only the diagonal tile
#pragma unroll
        for (int ki = 0; ki < 4; ++ki)
#pragma unroll
          for (int qi = 0; qi < 2; ++qi)
#pragma unroll
            for (int r = 0; r < 4; ++r) {
              const int kcol = kt * 64 + ki * 16 + quad * 4 + r;
              const int qrow = q0 + qi * 16 + l15;
              if (kcol > qrow) st[ki][qi][r] = -__builtin_inff();
            }
      }
      // p = exp2(s); per-lane partial row sums (q=l15)
#pragma unroll
      for (int ki = 0; ki < 4; ++ki)
#pragma unroll
        for (int qi = 0; qi < 2; ++qi) {
#pragma unroll
          for (int r = 0; r < 4; ++r)
            st[ki][qi][r] = __builtin_amdgcn_exp2f(st[ki][qi][r]);
          lsumv[qi] += st[ki][qi];
        }
      // pack P into bf16x8 A-fragments for 16x16x32 PV
      bf16x8 pa8[2][2];
#pragma unroll
      for (int ki2 = 0; ki2 < 2; ++ki2)
#pragma unroll
        for (int qi = 0; qi < 2; ++qi) {
          bf16x8 p;
#pragma unroll
          for (int r = 0; r < 4; ++r) {
            p[r] = (bf16)st[2 * ki2][qi][r];
            p[r + 4] = (bf16)st[2 * ki2 + 1][qi][r];
          }
          pa8[ki2][qi] = p;
        }
      // PV: O[q][d] += P·V via 16x16x32; V read as one b128 per (di,ki2)
      __builtin_amdgcn_s_setprio(1);
#pragma unroll
      for (int di = 0; di < 4; ++di)
#pragma unroll
        for (int ki2 = 0; ki2 < 2; ++ki2) {
          bf16x8 vv = *(const bf16x8*)&Vs[cur][(di * 16 + l15) * 72 + ki2 * 32 +
                                              quad * 8];
#pragma unroll
          for (int qi = 0; qi < 2; ++qi)
            oacc[qi][di] = __builtin_amdgcn_mfma_f32_16x16x32_bf16(
                pa8[ki2][qi], vv, oacc[qi][di], 0, 0, 0);
        }
      __builtin_amdgcn_s_setprio(0);
    }
    if (pre) {  // write prefetched tile into the other buffer
      const int nxt = cur ^ 1;
      *(uint4*)&Ks[nxt][srow * 72 + sc] = pk0;
      *(uint4*)&Ks[nxt][(srow + 32) * 72 + sc] = pk1;
      *(uint2*)&Vs[nxt][srow * 72 + vp0] = make_uint2(pv0.x, pv0.y);
      *(uint2*)&Vs[nxt][srow * 72 + vp0 + 8] = make_uint2(pv0.z, pv0.w);
      *(uint2*)&Vs[nxt][(srow + 32) * 72 + vp0] = make_uint2(pv1.x, pv1.y);
      *(uint2*)&Vs[nxt][(srow + 32) * 72 + vp0 + 8] = make_uint2(pv1.z, pv1.w);
    }
  }

  // epilogue: transpose l partials (q=l15 -> q=quad*4+r), divide, store
#pragma unroll
  for (int qi = 0; qi < 2; ++qi)
    Ls[wave][qi][quad][l15] =
        lsumv[qi][0] + lsumv[qi][1] + lsumv[qi][2] + lsumv[qi][3];
  // wave-private region; compiler inserts lgkmcnt before dependent reads
#pragma unroll
  for (int qi = 0; qi < 2; ++qi)
#pragma unroll
    for (int r = 0; r < 4; ++r) {
      const int rloc = quad * 4 + r;
      const float l = Ls[wave][qi][0][rloc] + Ls[wave][qi][1][rloc] +
                      Ls[wave][qi][2][rloc] + Ls[wave][qi][3][rloc];
      const float inv = 1.f / l;
      const int t = q0 + qi * 16 + rloc;
#pragma unroll
      for (int di = 0; di < 4; ++di) {
        const int d = di * 16 + l15;
        ob[((size_t)b * 2048 + t) * 1024 + h * 64 + d] =
            (bf16)(oacc[qi][di][r] * inv);
      }
    }
}

// ---------------------------------------------------------------- launch
extern "C" void kernel_launch(void* const* d_in, const int* in_sizes, int n_in,
                              void* d_out, int out_size, void* d_ws,
                              size_t ws_size, hipStream_t stream) {
  const float* x = (const float*)d_in[0];
  const float* w_qkv = (const float*)d_in[1];
  const float* b_qkv = (const float*)d_in[2];
  const float* w_proj = (const float*)d_in[3];
  const float* b_proj = (const float*)d_in[4];
  float* out = (float*)d_out;

  const int B = 4, T = 2048, C = 1024;
  const size_t nx = (size_t)B * T * C;  // 8388608

  char* ws = (char*)d_ws;
  bf16* xb = (bf16*)ws;      ws += nx * 2;
  bf16* wqkvb = (bf16*)ws;   ws += (size_t)3 * C * C * 2;
  bf16* wprojb = (bf16*)ws;  ws += (size_t)C * C * 2;
  bf16* qb = (bf16*)ws;      ws += nx * 2;
  bf16* kbuf = (bf16*)ws;    ws += nx * 2;
  bf16* vtb = (bf16*)ws;     ws += nx * 2;
  bf16* attb = (bf16*)ws;    ws += nx * 2;   // total 88 MB

  const int n0 = (int)(nx / 4), n1 = 3 * C * C / 4, n2 = C * C / 4;
  cvt3_f32_bf16<<<(n0 + n1 + n2 + 255) / 256, 256, 0, stream>>>(
      x, xb, n0, w_qkv, wqkvb, n1, w_proj, wprojb, n2);

  dim3 g1(64, 24);  // M/128, 3C/128 — 1536 blocks
  gemm_bt<1><<<g1, 256, 0, stream>>>(xb, wqkvb, b_qkv, nullptr, qb, kbuf, vtb,
                                     B * T, 3 * C, C);
  dim3 g2(64, 16);  // B*H x qt (balanced map) — 1024 blocks, all co-resident
  flash_attn<<<g2, 256, 0, stream>>>(qb, kbuf, vtb, attb);

  dim3 g3(64, 8);   // M/128, C/128 — 512 blocks
  gemm_bt<0><<<g3, 256, 0, stream>>>(attb, wprojb, b_proj, out, nullptr,
                                     nullptr, nullptr, B * T, C, C);
}